// Round 1
// baseline (325.916 us; speedup 1.0000x reference)
//
#include <hip/hip_runtime.h>

#define NB   4
#define CIN  64
#define COUT 64
#define HH   160
#define WW   160
#define HW   (HH * WW)

// ---------------------------------------------------------------------------
// Pre-pass: transpose weight [O][C][3][3] -> wt[t][c][o]  (t = ky*3+kx)
// so the main kernel reads 64 consecutive o's at a wave-uniform address
// (compiler scalarizes -> s_load, inner loop becomes v_fmac v, s, v).
// ---------------------------------------------------------------------------
__global__ void wt_transpose_kernel(const float* __restrict__ w,
                                    float* __restrict__ wt) {
    int i = blockIdx.x * 256 + threadIdx.x;       // i = (t*64 + c)*64 + o
    if (i < 9 * CIN * COUT) {
        int o = i & 63;
        int c = (i >> 6) & 63;
        int t = i >> 12;
        wt[i] = w[(o * CIN + c) * 9 + t];
    }
}

// ---------------------------------------------------------------------------
// Main kernel: one wave (64 lanes) per 64 consecutive output pixels.
// lane = pixel; each lane accumulates all 64 output channels in VGPRs.
// Weights are wave-uniform (SGPR); per (tap,c) we do 4 near-coalesced
// corner gathers + 64 fmacs. Gathers are software-pipelined one c ahead.
// ---------------------------------------------------------------------------
__global__ __launch_bounds__(64) void pdconv_kernel(
    const float* __restrict__ in,        // [B][CIN][H][W]
    const float* __restrict__ wt,        // [9][CIN][COUT]
    const float* __restrict__ rate_map,  // [B][1][H][W]
    const float* __restrict__ bias,      // [COUT]
    float* __restrict__ out)             // [B][COUT][H][W]
{
    const int lane = threadIdx.x;
    const int p    = blockIdx.x * 64 + lane;   // flat pixel over (b,y,x)
    const int b    = p / HW;                   // 25600 % 64 == 0: wave stays in one image
    const int pix  = p - b * HW;
    const int y    = pix / WW;
    const int x    = pix - y * WW;

    const float rate = rate_map[p];            // rate_map is (B,1,H,W) -> flat == p
    const float fy = (float)y, fx = (float)x;

    float acc[COUT];
#pragma unroll
    for (int o = 0; o < COUT; ++o) acc[o] = bias[o];

    const float* img = in + (size_t)b * CIN * HW;

#pragma unroll 1
    for (int t = 0; t < 9; ++t) {
        const int ky = t / 3;
        const int kx = t - 3 * ky;

        // Per-pixel fractional sample position (matches reference formulas)
        const float sy  = fy + (float)(ky - 1) * rate;
        const float sx  = fx + (float)(kx - 1) * rate;
        const float y0f = floorf(sy), x0f = floorf(sx);
        const float wy  = sy - y0f,   wx  = sx - x0f;
        const int   y0  = (int)y0f,   x0  = (int)x0f;
        const int   y1  = y0 + 1,     x1  = x0 + 1;

        const float omwy = 1.0f - wy, omwx = 1.0f - wx;
        const float vy0 = (y0 >= 0 && y0 < HH) ? 1.0f : 0.0f;
        const float vy1 = (y1 >= 0 && y1 < HH) ? 1.0f : 0.0f;
        const float vx0 = (x0 >= 0 && x0 < WW) ? 1.0f : 0.0f;
        const float vx1 = (x1 >= 0 && x1 < WW) ? 1.0f : 0.0f;

        const float c00 = omwy * omwx * vy0 * vx0;
        const float c01 = omwy * wx   * vy0 * vx1;
        const float c10 = wy   * omwx * vy1 * vx0;
        const float c11 = wy   * wx   * vy1 * vx1;

        const int cy0 = min(max(y0, 0), HH - 1);
        const int cy1 = min(max(y1, 0), HH - 1);
        const int cx0 = min(max(x0, 0), WW - 1);
        const int cx1 = min(max(x1, 0), WW - 1);

        const int i00 = cy0 * WW + cx0;
        const int i01 = cy0 * WW + cx1;
        const int i10 = cy1 * WW + cx0;
        const int i11 = cy1 * WW + cx1;

        const float* wrow = wt + t * (CIN * COUT);

        // software-pipelined over c: gathers for c+1 issue before c's fmacs
        float v00 = img[i00], v01 = img[i01], v10 = img[i10], v11 = img[i11];
#pragma unroll 1
        for (int c = 0; c < CIN - 1; ++c) {
            const float a = c00 * v00 + c01 * v01 + c10 * v10 + c11 * v11;
            const float* nxt = img + (size_t)(c + 1) * HW;
            v00 = nxt[i00]; v01 = nxt[i01]; v10 = nxt[i10]; v11 = nxt[i11];
            const float* wr = wrow + c * COUT;  // wave-uniform -> s_load
#pragma unroll
            for (int o = 0; o < COUT; ++o)
                acc[o] = fmaf(wr[o], a, acc[o]);
        }
        {   // epilogue c = CIN-1
            const float a = c00 * v00 + c01 * v01 + c10 * v10 + c11 * v11;
            const float* wr = wrow + (CIN - 1) * COUT;
#pragma unroll
            for (int o = 0; o < COUT; ++o)
                acc[o] = fmaf(wr[o], a, acc[o]);
        }
    }

    float* op = out + (size_t)b * COUT * HW + pix;
#pragma unroll
    for (int o = 0; o < COUT; ++o)
        op[(size_t)o * HW] = acc[o];
}

extern "C" void kernel_launch(void* const* d_in, const int* in_sizes, int n_in,
                              void* d_out, int out_size, void* d_ws, size_t ws_size,
                              hipStream_t stream) {
    (void)in_sizes; (void)n_in; (void)out_size; (void)ws_size;
    const float* in   = (const float*)d_in[0];
    const float* w    = (const float*)d_in[1];
    const float* rm   = (const float*)d_in[2];
    const float* bias = (const float*)d_in[3];
    float* out = (float*)d_out;
    float* wtb = (float*)d_ws;   // 147,456 B scratch for transposed weight

    hipLaunchKernelGGL(wt_transpose_kernel, dim3(144), dim3(256), 0, stream, w, wtb);

    const int nwaves = (NB * HW) / 64;  // 1600
    hipLaunchKernelGGL(pdconv_kernel, dim3(nwaves), dim3(64), 0, stream,
                       in, wtb, rm, bias, out);
}